// Round 1
// baseline (585.914 us; speedup 1.0000x reference)
//
#include <hip/hip_runtime.h>
#include <hip/hip_bf16.h>
#include <stdint.h>

// Problem constants (S=2048, B=4, H=1024, F=4096, E=8)
#define SB   8192
#define HDIM 1024
#define FDIM 4096
#define EDIM 8

typedef __bf16 bf16x8 __attribute__((ext_vector_type(8)));
typedef float  f32x4  __attribute__((ext_vector_type(4)));

__device__ __forceinline__ void g2l16(const void* g, void* l) {
  __builtin_amdgcn_global_load_lds(
      (const __attribute__((address_space(1))) uint32_t*)g,
      (__attribute__((address_space(3))) uint32_t*)l, 16, 0, 0);
}

__device__ __forceinline__ unsigned short f2bf(float f) {
  __hip_bfloat16 b = __float2bfloat16(f);
  return *reinterpret_cast<unsigned short*>(&b);
}

// ---------------- cast fp32 -> bf16 (vectorized) ----------------
__global__ void cast_bf16_kernel(const float4* __restrict__ in,
                                 ushort4* __restrict__ out, int n4) {
  int i = blockIdx.x * blockDim.x + threadIdx.x;
  if (i < n4) {
    float4 v = in[i];
    ushort4 o;
    o.x = f2bf(v.x); o.y = f2bf(v.y); o.z = f2bf(v.z); o.w = f2bf(v.w);
    out[i] = o;
  }
}

// ---------------- lambda: lam[e] = gb2[e] + dot(colsum, gw2[e,:]) / 8192 ----
__global__ void lam_kernel(const float* __restrict__ colsum,
                           const float* __restrict__ gw2,
                           const float* __restrict__ gb2,
                           float* __restrict__ lam) {
  __shared__ float red[256];
  const int tid = threadIdx.x;
  for (int e = 0; e < EDIM; ++e) {
    float p = 0.f;
    for (int h = tid; h < HDIM; h += 256) p += colsum[h] * gw2[e * HDIM + h];
    red[tid] = p;
    __syncthreads();
    for (int s = 128; s > 0; s >>= 1) {
      if (tid < s) red[tid] += red[tid + s];
      __syncthreads();
    }
    if (tid == 0) lam[e] = gb2[e] + red[0] * (1.f / 8192.f);
    __syncthreads();
  }
}

// ---------------- merge weights: out_bf16 = base + sum_e lam[e]*tv[e] ------
__global__ void merge_w_kernel(const float4* __restrict__ base,
                               const float4* __restrict__ tv,
                               const float* __restrict__ lam,
                               ushort4* __restrict__ outw, int n4) {
  int i = blockIdx.x * blockDim.x + threadIdx.x;
  if (i >= n4) return;
  float l[EDIM];
#pragma unroll
  for (int e = 0; e < EDIM; ++e) l[e] = lam[e];
  float4 v = base[i];
#pragma unroll
  for (int e = 0; e < EDIM; ++e) {
    float4 t = tv[(size_t)e * n4 + i];
    v.x += l[e] * t.x; v.y += l[e] * t.y; v.z += l[e] * t.z; v.w += l[e] * t.w;
  }
  ushort4 o;
  o.x = f2bf(v.x); o.y = f2bf(v.y); o.z = f2bf(v.z); o.w = f2bf(v.w);
  outw[i] = o;
}

// ---------------- merge biases (fp32 out, tiny) ----------------------------
__global__ void merge_b_kernel(const float* __restrict__ base,
                               const float* __restrict__ tv,
                               const float* __restrict__ lam,
                               float* __restrict__ outb, int n) {
  int i = blockIdx.x * blockDim.x + threadIdx.x;
  if (i >= n) return;
  float v = base[i];
#pragma unroll
  for (int e = 0; e < EDIM; ++e) v += lam[e] * tv[(size_t)e * n + i];
  outb[i] = v;
}

// ---------------- MFMA bt-GEMM: C[M,N] = A[M,K] * B[N,K]^T ------------------
// 128x128 block tile, BK=32, 256 threads (4 waves, 2x2 of 64x64 wave tiles).
// MODE 0: bias+relu, column-sum atomicAdd into Cout (float* colsum[N])
// MODE 1: bias+relu, store bf16 to Cout[M,N]
// MODE 2: bias,      store fp32 to Cout[M,N]
template <int MODE>
__global__ void gemm_bt(const ushort* __restrict__ A, const ushort* __restrict__ B,
                        const float* __restrict__ bias, void* __restrict__ Cout,
                        int M, int N, int K) {
  __shared__ __align__(16) ushort As[128 * 32];
  __shared__ __align__(16) ushort Bs[128 * 32];

  const int tid  = threadIdx.x;
  const int lane = tid & 63;
  const int wave = tid >> 6;
  const int wm = wave >> 1, wn = wave & 1;
  const int lr = lane & 15, lq = lane >> 4;
  const int m0 = blockIdx.y * 128, n0 = blockIdx.x * 128;

  // staging: issue i covers rows [i*64, i*64+64), thread t -> row i*64+(t>>2),
  // cols (t&3)*8 .. +8.  LDS element offset = i*2048 + t*8 (lane-linear,
  // matches global_load_lds wave-uniform-base + lane*16 requirement).
  const int srow = tid >> 2;
  const int scol = (tid & 3) * 8;

  f32x4 acc[4][4];
#pragma unroll
  for (int i = 0; i < 4; ++i)
#pragma unroll
    for (int j = 0; j < 4; ++j)
#pragma unroll
      for (int r = 0; r < 4; ++r) acc[i][j][r] = 0.f;

  for (int k0 = 0; k0 < K; k0 += 32) {
#pragma unroll
    for (int i = 0; i < 2; ++i) {
      g2l16(A + (size_t)(m0 + i * 64 + srow) * K + (k0 + scol),
            &As[i * 2048 + tid * 8]);
      g2l16(B + (size_t)(n0 + i * 64 + srow) * K + (k0 + scol),
            &Bs[i * 2048 + tid * 8]);
    }
    __syncthreads();

    bf16x8 afr[4], bfr[4];
#pragma unroll
    for (int mi = 0; mi < 4; ++mi)
      afr[mi] = *reinterpret_cast<const bf16x8*>(
          &As[(wm * 64 + mi * 16 + lr) * 32 + lq * 8]);
#pragma unroll
    for (int ni = 0; ni < 4; ++ni)
      bfr[ni] = *reinterpret_cast<const bf16x8*>(
          &Bs[(wn * 64 + ni * 16 + lr) * 32 + lq * 8]);
#pragma unroll
    for (int mi = 0; mi < 4; ++mi)
#pragma unroll
      for (int ni = 0; ni < 4; ++ni)
        acc[mi][ni] = __builtin_amdgcn_mfma_f32_16x16x32_bf16(
            afr[mi], bfr[ni], acc[mi][ni], 0, 0, 0);
    __syncthreads();
  }

  // epilogue.  C/D layout (verified m89/m91): col = lane&15, row = lq*4+reg.
  const int gm = m0 + wm * 64;
  const int gn = n0 + wn * 64;
  if (MODE == 0) {
    float* colsum = (float*)Cout;
#pragma unroll
    for (int ni = 0; ni < 4; ++ni) {
      const int col = gn + ni * 16 + lr;
      const float bv = bias[col];
      float p = 0.f;
#pragma unroll
      for (int mi = 0; mi < 4; ++mi)
#pragma unroll
        for (int r = 0; r < 4; ++r) {
          float v = acc[mi][ni][r] + bv;
          p += v > 0.f ? v : 0.f;
        }
      p += __shfl_xor(p, 16);
      p += __shfl_xor(p, 32);
      if (lq == 0) atomicAdd(&colsum[col], p);
    }
  } else if (MODE == 1) {
    __hip_bfloat16* C = (__hip_bfloat16*)Cout;
#pragma unroll
    for (int ni = 0; ni < 4; ++ni) {
      const int col = gn + ni * 16 + lr;
      const float bv = bias[col];
#pragma unroll
      for (int mi = 0; mi < 4; ++mi)
#pragma unroll
        for (int r = 0; r < 4; ++r) {
          const int row = gm + mi * 16 + lq * 4 + r;
          float v = acc[mi][ni][r] + bv;
          v = v > 0.f ? v : 0.f;
          C[(size_t)row * N + col] = __float2bfloat16(v);
        }
    }
  } else {
    float* C = (float*)Cout;
#pragma unroll
    for (int ni = 0; ni < 4; ++ni) {
      const int col = gn + ni * 16 + lr;
      const float bv = bias[col];
#pragma unroll
      for (int mi = 0; mi < 4; ++mi)
#pragma unroll
        for (int r = 0; r < 4; ++r) {
          const int row = gm + mi * 16 + lq * 4 + r;
          C[(size_t)row * N + col] = acc[mi][ni][r] + bv;
        }
    }
  }
}

// ---------------------------------------------------------------------------
extern "C" void kernel_launch(void* const* d_in, const int* in_sizes, int n_in,
                              void* d_out, int out_size, void* d_ws, size_t ws_size,
                              hipStream_t stream) {
  const float* X   = (const float*)d_in[0];   // [S,B,H]
  const float* gw1 = (const float*)d_in[1];   // [H,H]
  const float* gb1 = (const float*)d_in[2];   // [H]
  const float* gw2 = (const float*)d_in[3];   // [E,H]
  const float* gb2 = (const float*)d_in[4];   // [E]
  const float* bw1 = (const float*)d_in[5];   // [F,H]
  const float* bb1 = (const float*)d_in[6];   // [F]
  const float* bw2 = (const float*)d_in[7];   // [H,F]
  const float* bb2 = (const float*)d_in[8];   // [H]
  const float* tw1 = (const float*)d_in[9];   // [E,F,H]
  const float* tb1 = (const float*)d_in[10];  // [E,F]
  const float* tw2 = (const float*)d_in[11];  // [E,H,F]
  const float* tb2 = (const float*)d_in[12];  // [E,H]
  float* out = (float*)d_out;                 // [S,B,H]

  // workspace carve (256B aligned)
  size_t off = 0;
  auto carve = [&](size_t bytes) -> void* {
    void* p = (char*)d_ws + off;
    off += (bytes + 255) & ~(size_t)255;
    return p;
  };
  ushort* Xbf   = (ushort*)carve((size_t)SB * HDIM * 2);     // X in bf16
  ushort* gw1bf = (ushort*)carve((size_t)HDIM * HDIM * 2);   // gate w1 bf16
  ushort* w1m   = (ushort*)carve((size_t)FDIM * HDIM * 2);   // merged w1 bf16
  ushort* w2m   = (ushort*)carve((size_t)HDIM * FDIM * 2);   // merged w2 bf16
  ushort* hbuf  = (ushort*)carve((size_t)SB * FDIM * 2);     // h bf16
  float* b1m    = (float*)carve(FDIM * 4);
  float* b2m    = (float*)carve(HDIM * 4);
  float* colsum = (float*)carve(HDIM * 4);
  float* lam    = (float*)carve(EDIM * 4);

  // 1) casts to bf16
  {
    int n4 = SB * HDIM / 4;
    cast_bf16_kernel<<<(n4 + 255) / 256, 256, 0, stream>>>(
        (const float4*)X, (ushort4*)Xbf, n4);
    n4 = HDIM * HDIM / 4;
    cast_bf16_kernel<<<(n4 + 255) / 256, 256, 0, stream>>>(
        (const float4*)gw1, (ushort4*)gw1bf, n4);
  }

  // 2) zero colsum accumulator (ws is poisoned before each call)
  hipMemsetAsync(colsum, 0, HDIM * sizeof(float), stream);

  // 3) gate GEMM -> relu -> column sums  (M=8192, N=1024, K=1024)
  gemm_bt<0><<<dim3(HDIM / 128, SB / 128), 256, 0, stream>>>(
      Xbf, gw1bf, gb1, colsum, SB, HDIM, HDIM);

  // 4) lambda
  lam_kernel<<<1, 256, 0, stream>>>(colsum, gw2, gb2, lam);

  // 5) merge weights + biases
  {
    int n4 = FDIM * HDIM / 4;
    merge_w_kernel<<<(n4 + 255) / 256, 256, 0, stream>>>(
        (const float4*)bw1, (const float4*)tw1, lam, (ushort4*)w1m, n4);
    merge_w_kernel<<<(n4 + 255) / 256, 256, 0, stream>>>(
        (const float4*)bw2, (const float4*)tw2, lam, (ushort4*)w2m, n4);
    merge_b_kernel<<<(FDIM + 255) / 256, 256, 0, stream>>>(bb1, tb1, lam, b1m, FDIM);
    merge_b_kernel<<<(HDIM + 255) / 256, 256, 0, stream>>>(bb2, tb2, lam, b2m, HDIM);
  }

  // 6) h = relu(X @ w1m^T + b1m)   (M=8192, N=4096, K=1024), bf16 out
  gemm_bt<1><<<dim3(FDIM / 128, SB / 128), 256, 0, stream>>>(
      Xbf, w1m, b1m, hbuf, SB, FDIM, HDIM);

  // 7) out = h @ w2m^T + b2m       (M=8192, N=1024, K=4096), fp32 out
  gemm_bt<2><<<dim3(HDIM / 128, SB / 128), 256, 0, stream>>>(
      hbuf, w2m, b2m, out, SB, HDIM, FDIM);
}

// Round 2
// 576.594 us; speedup vs baseline: 1.0162x; 1.0162x over previous
//
#include <hip/hip_runtime.h>
#include <hip/hip_bf16.h>
#include <stdint.h>

// Problem constants (S=2048, B=4, H=1024, F=4096, E=8)
#define SB   8192
#define HDIM 1024
#define FDIM 4096
#define EDIM 8

typedef __bf16 bf16x8 __attribute__((ext_vector_type(8)));
typedef float  f32x4  __attribute__((ext_vector_type(4)));

__device__ __forceinline__ void g2l16(const void* g, void* l) {
  __builtin_amdgcn_global_load_lds(
      (const __attribute__((address_space(1))) uint32_t*)g,
      (__attribute__((address_space(3))) uint32_t*)l, 16, 0, 0);
}

__device__ __forceinline__ unsigned short f2bf(float f) {
  __hip_bfloat16 b = __float2bfloat16(f);
  return *reinterpret_cast<unsigned short*>(&b);
}

// ---------------- cast fp32 -> bf16 (vectorized) ----------------
__global__ void cast_bf16_kernel(const float4* __restrict__ in,
                                 ushort4* __restrict__ out, int n4) {
  int i = blockIdx.x * blockDim.x + threadIdx.x;
  if (i < n4) {
    float4 v = in[i];
    ushort4 o;
    o.x = f2bf(v.x); o.y = f2bf(v.y); o.z = f2bf(v.z); o.w = f2bf(v.w);
    out[i] = o;
  }
}

// ---------------- lambda: lam[e] = gb2[e] + dot(colsum, gw2[e,:]) / 8192 ----
__global__ void lam_kernel(const float* __restrict__ colsum,
                           const float* __restrict__ gw2,
                           const float* __restrict__ gb2,
                           float* __restrict__ lam) {
  __shared__ float red[256];
  const int tid = threadIdx.x;
  for (int e = 0; e < EDIM; ++e) {
    float p = 0.f;
    for (int h = tid; h < HDIM; h += 256) p += colsum[h] * gw2[e * HDIM + h];
    red[tid] = p;
    __syncthreads();
    for (int s = 128; s > 0; s >>= 1) {
      if (tid < s) red[tid] += red[tid + s];
      __syncthreads();
    }
    if (tid == 0) lam[e] = gb2[e] + red[0] * (1.f / 8192.f);
    __syncthreads();
  }
}

// ---------------- merge weights: out_bf16 = base + sum_e lam[e]*tv[e] ------
__global__ void merge_w_kernel(const float4* __restrict__ base,
                               const float4* __restrict__ tv,
                               const float* __restrict__ lam,
                               ushort4* __restrict__ outw, int n4) {
  int i = blockIdx.x * blockDim.x + threadIdx.x;
  if (i >= n4) return;
  float l[EDIM];
#pragma unroll
  for (int e = 0; e < EDIM; ++e) l[e] = lam[e];
  float4 v = base[i];
#pragma unroll
  for (int e = 0; e < EDIM; ++e) {
    float4 t = tv[(size_t)e * n4 + i];
    v.x += l[e] * t.x; v.y += l[e] * t.y; v.z += l[e] * t.z; v.w += l[e] * t.w;
  }
  ushort4 o;
  o.x = f2bf(v.x); o.y = f2bf(v.y); o.z = f2bf(v.z); o.w = f2bf(v.w);
  outw[i] = o;
}

// ---------------- merge biases (fp32 out, tiny) ----------------------------
__global__ void merge_b_kernel(const float* __restrict__ base,
                               const float* __restrict__ tv,
                               const float* __restrict__ lam,
                               float* __restrict__ outb, int n) {
  int i = blockIdx.x * blockDim.x + threadIdx.x;
  if (i >= n) return;
  float v = base[i];
#pragma unroll
  for (int e = 0; e < EDIM; ++e) v += lam[e] * tv[(size_t)e * n + i];
  outb[i] = v;
}

// ---------------- MFMA bt-GEMM: C[M,N] = A[M,K] * B[N,K]^T ------------------
// BM x 128 block tile, BK=32, 256 threads (4 waves, 2x2 of (BM/2)x64 wave
// tiles). BM in {64,128}.
// XCD-aware swizzle: HW dispatches block b to XCD b%8; we give each XCD a
// contiguous band of M-tiles sweeping all N-tiles, so its L2 working set is
// (band of A) + B instead of scattered A rows.
// MODE 0: bias+relu, column-sum atomicAdd into Cout (float* colsum[N])
// MODE 1: bias+relu, store bf16 to Cout[M,N]
// MODE 2: bias,      store fp32 to Cout[M,N]
template <int MODE, int BM>
__global__ void gemm_bt(const ushort* __restrict__ A, const ushort* __restrict__ B,
                        const float* __restrict__ bias, void* __restrict__ Cout,
                        int M, int N, int K) {
  constexpr int MI = BM / 32;  // acc tiles per wave in M (wave tile = BM/2 rows)
  __shared__ __align__(16) ushort As[BM * 32];
  __shared__ __align__(16) ushort Bs[128 * 32];

  const int tid  = threadIdx.x;
  const int lane = tid & 63;
  const int wave = tid >> 6;
  const int wm = wave >> 1, wn = wave & 1;
  const int lr = lane & 15, lq = lane >> 4;

  // XCD swizzle (requires gridDim.y % 8 == 0)
  const int bid = blockIdx.y * gridDim.x + blockIdx.x;
  const int gx  = gridDim.x;
  const int Yc  = gridDim.y >> 3;
  const int xcd = bid & 7;
  const int t   = bid >> 3;
  const int tq  = t / gx;
  const int ty  = xcd * Yc + tq;
  const int tx  = t - tq * gx;
  const int m0 = ty * BM, n0 = tx * 128;

  // staging: issue i covers 64 rows; thread t -> row i*64+(t>>2),
  // cols (t&3)*8 .. +8.  LDS element offset = i*2048 + t*8 (lane-linear,
  // matches global_load_lds wave-uniform-base + lane*16 requirement).
  const int srow = tid >> 2;
  const int scol = (tid & 3) * 8;

  f32x4 acc[MI][4];
#pragma unroll
  for (int i = 0; i < MI; ++i)
#pragma unroll
    for (int j = 0; j < 4; ++j)
#pragma unroll
      for (int r = 0; r < 4; ++r) acc[i][j][r] = 0.f;

  for (int k0 = 0; k0 < K; k0 += 32) {
#pragma unroll
    for (int i = 0; i < BM / 64; ++i)
      g2l16(A + (size_t)(m0 + i * 64 + srow) * K + (k0 + scol),
            &As[i * 2048 + tid * 8]);
#pragma unroll
    for (int i = 0; i < 2; ++i)
      g2l16(B + (size_t)(n0 + i * 64 + srow) * K + (k0 + scol),
            &Bs[i * 2048 + tid * 8]);
    __syncthreads();

    bf16x8 afr[MI], bfr[4];
#pragma unroll
    for (int mi = 0; mi < MI; ++mi)
      afr[mi] = *reinterpret_cast<const bf16x8*>(
          &As[(wm * (BM / 2) + mi * 16 + lr) * 32 + lq * 8]);
#pragma unroll
    for (int ni = 0; ni < 4; ++ni)
      bfr[ni] = *reinterpret_cast<const bf16x8*>(
          &Bs[(wn * 64 + ni * 16 + lr) * 32 + lq * 8]);
#pragma unroll
    for (int mi = 0; mi < MI; ++mi)
#pragma unroll
      for (int ni = 0; ni < 4; ++ni)
        acc[mi][ni] = __builtin_amdgcn_mfma_f32_16x16x32_bf16(
            afr[mi], bfr[ni], acc[mi][ni], 0, 0, 0);
    __syncthreads();
  }

  // epilogue.  C/D layout (verified m89/m91): col = lane&15, row = lq*4+reg.
  const int gm = m0 + wm * (BM / 2);
  const int gn = n0 + wn * 64;
  if (MODE == 0) {
    float* colsum = (float*)Cout;
#pragma unroll
    for (int ni = 0; ni < 4; ++ni) {
      const int col = gn + ni * 16 + lr;
      const float bv = bias[col];
      float p = 0.f;
#pragma unroll
      for (int mi = 0; mi < MI; ++mi)
#pragma unroll
        for (int r = 0; r < 4; ++r) {
          float v = acc[mi][ni][r] + bv;
          p += v > 0.f ? v : 0.f;
        }
      p += __shfl_xor(p, 16);
      p += __shfl_xor(p, 32);
      if (lq == 0) atomicAdd(&colsum[col], p);
    }
  } else if (MODE == 1) {
    __hip_bfloat16* C = (__hip_bfloat16*)Cout;
#pragma unroll
    for (int ni = 0; ni < 4; ++ni) {
      const int col = gn + ni * 16 + lr;
      const float bv = bias[col];
#pragma unroll
      for (int mi = 0; mi < MI; ++mi)
#pragma unroll
        for (int r = 0; r < 4; ++r) {
          const int row = gm + mi * 16 + lq * 4 + r;
          float v = acc[mi][ni][r] + bv;
          v = v > 0.f ? v : 0.f;
          C[(size_t)row * N + col] = __float2bfloat16(v);
        }
    }
  } else {
    float* C = (float*)Cout;
#pragma unroll
    for (int ni = 0; ni < 4; ++ni) {
      const int col = gn + ni * 16 + lr;
      const float bv = bias[col];
#pragma unroll
      for (int mi = 0; mi < MI; ++mi)
#pragma unroll
        for (int r = 0; r < 4; ++r) {
          const int row = gm + mi * 16 + lq * 4 + r;
          C[(size_t)row * N + col] = acc[mi][ni][r] + bv;
        }
    }
  }
}

// ---------------------------------------------------------------------------
extern "C" void kernel_launch(void* const* d_in, const int* in_sizes, int n_in,
                              void* d_out, int out_size, void* d_ws, size_t ws_size,
                              hipStream_t stream) {
  const float* X   = (const float*)d_in[0];   // [S,B,H]
  const float* gw1 = (const float*)d_in[1];   // [H,H]
  const float* gb1 = (const float*)d_in[2];   // [H]
  const float* gw2 = (const float*)d_in[3];   // [E,H]
  const float* gb2 = (const float*)d_in[4];   // [E]
  const float* bw1 = (const float*)d_in[5];   // [F,H]
  const float* bb1 = (const float*)d_in[6];   // [F]
  const float* bw2 = (const float*)d_in[7];   // [H,F]
  const float* bb2 = (const float*)d_in[8];   // [H]
  const float* tw1 = (const float*)d_in[9];   // [E,F,H]
  const float* tb1 = (const float*)d_in[10];  // [E,F]
  const float* tw2 = (const float*)d_in[11];  // [E,H,F]
  const float* tb2 = (const float*)d_in[12];  // [E,H]
  float* out = (float*)d_out;                 // [S,B,H]

  // workspace carve (256B aligned)
  size_t off = 0;
  auto carve = [&](size_t bytes) -> void* {
    void* p = (char*)d_ws + off;
    off += (bytes + 255) & ~(size_t)255;
    return p;
  };
  ushort* Xbf   = (ushort*)carve((size_t)SB * HDIM * 2);     // X in bf16
  ushort* gw1bf = (ushort*)carve((size_t)HDIM * HDIM * 2);   // gate w1 bf16
  ushort* w1m   = (ushort*)carve((size_t)FDIM * HDIM * 2);   // merged w1 bf16
  ushort* w2m   = (ushort*)carve((size_t)HDIM * FDIM * 2);   // merged w2 bf16
  ushort* hbuf  = (ushort*)carve((size_t)SB * FDIM * 2);     // h bf16
  float* b1m    = (float*)carve(FDIM * 4);
  float* b2m    = (float*)carve(HDIM * 4);
  float* colsum = (float*)carve(HDIM * 4);
  float* lam    = (float*)carve(EDIM * 4);

  // 1) casts to bf16
  {
    int n4 = SB * HDIM / 4;
    cast_bf16_kernel<<<(n4 + 255) / 256, 256, 0, stream>>>(
        (const float4*)X, (ushort4*)Xbf, n4);
    n4 = HDIM * HDIM / 4;
    cast_bf16_kernel<<<(n4 + 255) / 256, 256, 0, stream>>>(
        (const float4*)gw1, (ushort4*)gw1bf, n4);
  }

  // 2) zero colsum accumulator (ws is poisoned before each call)
  hipMemsetAsync(colsum, 0, HDIM * sizeof(float), stream);

  // 3) gate GEMM -> relu -> column sums  (M=8192, N=1024, K=1024), BM=64
  gemm_bt<0, 64><<<dim3(HDIM / 128, SB / 64), 256, 0, stream>>>(
      Xbf, gw1bf, gb1, colsum, SB, HDIM, HDIM);

  // 4) lambda
  lam_kernel<<<1, 256, 0, stream>>>(colsum, gw2, gb2, lam);

  // 5) merge weights + biases
  {
    int n4 = FDIM * HDIM / 4;
    merge_w_kernel<<<(n4 + 255) / 256, 256, 0, stream>>>(
        (const float4*)bw1, (const float4*)tw1, lam, (ushort4*)w1m, n4);
    merge_w_kernel<<<(n4 + 255) / 256, 256, 0, stream>>>(
        (const float4*)bw2, (const float4*)tw2, lam, (ushort4*)w2m, n4);
    merge_b_kernel<<<(FDIM + 255) / 256, 256, 0, stream>>>(bb1, tb1, lam, b1m, FDIM);
    merge_b_kernel<<<(HDIM + 255) / 256, 256, 0, stream>>>(bb2, tb2, lam, b2m, HDIM);
  }

  // 6) h = relu(X @ w1m^T + b1m)   (M=8192, N=4096, K=1024), bf16 out, BM=128
  gemm_bt<1, 128><<<dim3(FDIM / 128, SB / 128), 256, 0, stream>>>(
      Xbf, w1m, b1m, hbuf, SB, FDIM, HDIM);

  // 7) out = h @ w2m^T + b2m       (M=8192, N=1024, K=4096), fp32 out, BM=64
  gemm_bt<2, 64><<<dim3(HDIM / 128, SB / 64), 256, 0, stream>>>(
      hbuf, w2m, b2m, out, SB, HDIM, FDIM);
}